// Round 20
// baseline (591.701 us; speedup 1.0000x reference)
//
#include <hip/hip_runtime.h>
#include <cstdint>

typedef _Float16 half2_t __attribute__((ext_vector_type(2)));

#define B_   128
#define T_   2048
#define E_   8
#define OUT_ 32
#define HID_ 64
#define KC_  8
#define TILE_A 128
#define NSEG 2
#define SPLIT 1088           // seg0 outputs [0,1088), seg1 outputs [1088,2048)
#define WUPC 2               // seg1 warmup chunks (2 x 64 = 128 steps)
#define CH_  64              // chunk length
#define NCHB 17              // chunks per block (1088 steps)

__device__ __forceinline__ float frcp(float x) { return __builtin_amdgcn_rcpf(x); }
__device__ __forceinline__ float exp2_(float x) {
#if __has_builtin(__builtin_amdgcn_exp2f)
  return __builtin_amdgcn_exp2f(x);
#else
  return exp2f(x);
#endif
}
__device__ __forceinline__ float fsig(float x) { return frcp(1.0f + __expf(-x)); }

__device__ __forceinline__ float fdot2_(half2_t a, half2_t b, float c) {
#if __has_builtin(__builtin_amdgcn_fdot2)
  return __builtin_amdgcn_fdot2(a, b, c, false);
#else
  return fmaf((float)a.x, (float)b.x, fmaf((float)a.y, (float)b.y, c));
#endif
}

__device__ __forceinline__ half2_t u2h2(unsigned u) {
  return __builtin_bit_cast(half2_t, u);
}
__device__ __forceinline__ half2_t packh2(float a, float b) {
  half2_t h; h.x = (_Float16)a; h.y = (_Float16)b; return h;
}

#define NLOG2E  (-1.4426950408889634f)
#define N2LOG2E (-2.8853900817779268f)

// Per-(b,t) scalar KAN pieces. All b-spline denominators fold to compile-time constants.
__device__ __forceinline__ void kan_scalars(float x, const float* gwr, const float* gbr,
                                            float& silu, float* gate, float* bs) {
  silu = x * fsig(x);
  float le[E_];
  float m = -1e30f;
#pragma unroll
  for (int e = 0; e < E_; ++e) { le[e] = fmaf(x, gwr[e], gbr[e]); m = fmaxf(m, le[e]); }
  float s = 0.f;
#pragma unroll
  for (int e = 0; e < E_; ++e) { gate[e] = __expf(le[e] - m); s += gate[e]; }
  float inv = frcp(s);
#pragma unroll
  for (int e = 0; e < E_; ++e) gate[e] *= inv;
  float g[12];
#pragma unroll
  for (int i = 0; i < 12; ++i) g[i] = (float)(i - 3) * 0.4f - 1.0f;
  float bb[11];
#pragma unroll
  for (int i = 0; i < 11; ++i) bb[i] = (x >= g[i] && x < g[i + 1]) ? 1.0f : 0.0f;
#pragma unroll
  for (int k = 1; k <= 3; ++k) {
#pragma unroll
    for (int i = 0; i < 11 - k; ++i) {
      const float dl = 1.0f / (g[i + k] - g[i]);
      const float dr = 1.0f / (g[i + k + 1] - g[i + 1]);
      float left  = (x - g[i]) * dl;
      float right = (g[i + k + 1] - x) * dr;
      bb[i] = left * bb[i] + right * bb[i + 1];
    }
  }
#pragma unroll
  for (int i = 0; i < KC_; ++i) bs[i] = bb[i];
}

#define DOTBLK(U, K0) { \
  const half2_t q0 = u2h2((U).x), q1 = u2h2((U).y), q2 = u2h2((U).z), q3 = u2h2((U).w); \
  ar0 = fdot2_(whhp[0][(K0)+0], q0, ar0); ar1 = fdot2_(whhp[0][(K0)+1], q1, ar1); \
  ar2 = fdot2_(whhp[0][(K0)+2], q2, ar2); ar3 = fdot2_(whhp[0][(K0)+3], q3, ar3); \
  az0 = fdot2_(whhp[1][(K0)+0], q0, az0); az1 = fdot2_(whhp[1][(K0)+1], q1, az1); \
  az2 = fdot2_(whhp[1][(K0)+2], q2, az2); az3 = fdot2_(whhp[1][(K0)+3], q3, az3); \
  an0 = fdot2_(whhp[2][(K0)+0], q0, an0); an1 = fdot2_(whhp[2][(K0)+1], q1, an1); \
  an2 = fdot2_(whhp[2][(K0)+2], q2, an2); an3 = fdot2_(whhp[2][(K0)+3], q3, an3); }

// ---------------- R13 skeleton (256 blocks, CH=64, NSEG=2, conv tail), producer
// arithmetic converted from v_dot2_f32_f16 to PLAIN F32 FMA. A/B test of the
// "dot2 issues ~8cyc -> producer ~1200cyc/t is dot2-bound" theory: both prior
// producer engines (readlane R12, LDS-packsw R13) measured ~1200 cyc/t and both
// used 32 dot2/t. f32 path: 80 fma/t @2cyc + 5 b128 LDS broadcast reads.
// Consumer & conv are R13 verbatim (single-variable change).
__global__ __launch_bounds__(256, 1) void fused10_kernel(
    const float* __restrict__ a, const float* __restrict__ d,
    const float* __restrict__ gwa, const float* __restrict__ gba,
    const float* __restrict__ bwa, const float* __restrict__ swa,
    const float* __restrict__ gwd, const float* __restrict__ gbd,
    const float* __restrict__ bwd, const float* __restrict__ swd,
    const float* __restrict__ cw, const float* __restrict__ cb,
    const float* __restrict__ wih_g, const float* __restrict__ whh_g,
    const float* __restrict__ bih_g, const float* __restrict__ bhh_g,
    float* __restrict__ out)
{
  __shared__ __align__(16) char smem_[64640];
  const int tid = threadIdx.x;

  // GRU LDS: xqrz @0 (32768) ; xqn @32768 (16384) ; packsw @49152 (15360,
  //          [3][64][20] f32, row: bs[0..7], gate[8..15], silu[16], pad) ;
  //          hbc @64512 (128)
  auto xqrz   = (unsigned (*)[CH_][64])smem_;
  auto xqn    = (_Float16 (*)[CH_][64])(smem_ + 32768);
  auto packsw = (float (*)[CH_][20])(smem_ + 49152);
  auto hbc    = (unsigned short*)(smem_ + 64512);

  const int bid = (int)blockIdx.x;
  const int b = bid & (B_ - 1);
  const int seg = bid >> 7;
  const int tstart = (seg == 0) ? 0 : (SPLIT - WUPC * CH_);   // 0 or 960
  const int wup = (seg == 0) ? 0 : WUPC;
  const int w = tid >> 6;
  const int ln = tid & 63;
  const size_t db = (size_t)b * T_;
  float* outrow = out + db * 96 + 32;
  const uint4* hq4 = (const uint4*)hbc;

  // ---- wave 0 (consumer): w_hh as f16 pairs, pre-scaled
  half2_t whhp[3][32];
  float bhh3[3];
  uint4 u0, u1, u2, u3, u4, u5, u6, u7;
  if (w == 0) {
#pragma unroll
    for (int g3 = 0; g3 < 3; ++g3) {
      const float sc = (g3 == 2) ? N2LOG2E : NLOG2E;
      const int g = g3 * 64 + ln;
#pragma unroll
      for (int i = 0; i < 64; i += 4) {
        const float4 v = *(const float4*)&whh_g[(size_t)g * 64 + i];
        whhp[g3][i / 2]     = packh2(v.x * sc, v.y * sc);
        whhp[g3][i / 2 + 1] = packh2(v.z * sc, v.w * sc);
      }
      bhh3[g3] = bhh_g[g] * sc;
    }
    hbc[ln] = __builtin_bit_cast(unsigned short, (_Float16)0.0f);
    asm volatile("" ::: "memory");
    u0 = hq4[0]; u1 = hq4[1]; u2 = hq4[2]; u3 = hq4[3];
    u4 = hq4[4]; u5 = hq4[5]; u6 = hq4[6]; u7 = hq4[7];
  }

  // ---- waves 1-3 (producers): folded weights in F32 for gate g = (w-1)*64 + ln
  float A_[E_];
  float Bef[E_][KC_];
  float bihr = 0.f;
  float gwrd[E_], gbrd[E_];
  const int p3 = (w >= 1) ? (w - 1) : 0;
  if (w >= 1) {
    const float sc = (p3 == 2) ? N2LOG2E : NLOG2E;
    const int g = p3 * 64 + ln;
    float wihr[32];
#pragma unroll
    for (int i = 0; i < 32; i += 4) {
      float4 v = *(const float4*)&wih_g[(size_t)g * 32 + i];
      wihr[i] = v.x * sc; wihr[i + 1] = v.y * sc;
      wihr[i + 2] = v.z * sc; wihr[i + 3] = v.w * sc;
    }
    bihr = bih_g[g] * sc;
#pragma unroll
    for (int e = 0; e < E_; ++e) { gwrd[e] = gwd[e]; gbrd[e] = gbd[e]; }
#pragma unroll
    for (int e = 0; e < E_; ++e) {
      float acc = 0.f;
#pragma unroll 4
      for (int c = 0; c < 32; c += 4) {
        const float4 bv = *(const float4*)&bwd[e * OUT_ + c];
        acc = fmaf(wihr[c], bv.x, acc);
        acc = fmaf(wihr[c + 1], bv.y, acc);
        acc = fmaf(wihr[c + 2], bv.z, acc);
        acc = fmaf(wihr[c + 3], bv.w, acc);
      }
      A_[e] = acc;
#pragma unroll
      for (int k = 0; k < KC_; ++k) Bef[e][k] = 0.f;
#pragma unroll 4
      for (int c = 0; c < 32; ++c) {
        const float4 s0 = *(const float4*)&swd[(e * OUT_ + c) * KC_ + 0];
        const float4 s1 = *(const float4*)&swd[(e * OUT_ + c) * KC_ + 4];
        const float wc = wihr[c];
        Bef[e][0] = fmaf(wc, s0.x, Bef[e][0]); Bef[e][1] = fmaf(wc, s0.y, Bef[e][1]);
        Bef[e][2] = fmaf(wc, s0.z, Bef[e][2]); Bef[e][3] = fmaf(wc, s0.w, Bef[e][3]);
        Bef[e][4] = fmaf(wc, s1.x, Bef[e][4]); Bef[e][5] = fmaf(wc, s1.y, Bef[e][5]);
        Bef[e][6] = fmaf(wc, s1.z, Bef[e][6]); Bef[e][7] = fmaf(wc, s1.w, Bef[e][7]);
      }
    }
  }

  float h = 0.0f;

  for (int ic = 0; ic <= NCHB; ++ic) {
    // ---------- producers: chunk ic -> xqrz/xqn[ic&1], ALL-F32 math ----------
    if (w >= 1 && ic < NCHB) {
      const int p = ic & 1;
      {
        const float x = d[db + tstart + ic * CH_ + ln];
        float silu, gate[E_], bs[KC_];
        kan_scalars(x, gwrd, gbrd, silu, gate, bs);
        float* prow = &packsw[p3][ln][0];
        *(float4*)&prow[0]  = *(float4*)&bs[0];
        *(float4*)&prow[4]  = *(float4*)&bs[4];
        *(float4*)&prow[8]  = *(float4*)&gate[0];
        *(float4*)&prow[12] = *(float4*)&gate[4];
        prow[16] = silu;
      }
      asm volatile("" ::: "memory");   // order pack-write before t-loop reads (intra-wave)
#pragma unroll 2
      for (int t = 0; t < CH_; ++t) {
        const float* pr = &packsw[p3][t][0];
        const float4 bsA = *(const float4*)&pr[0];
        const float4 bsB = *(const float4*)&pr[4];
        const float4 g0 = *(const float4*)&pr[8];
        const float4 g1 = *(const float4*)&pr[12];
        const float silu_t = pr[16];
        float acc = bihr;
#pragma unroll
        for (int e = 0; e < E_; ++e) {
          float in = silu_t * A_[e];
          in = fmaf(bsA.x, Bef[e][0], in); in = fmaf(bsA.y, Bef[e][1], in);
          in = fmaf(bsA.z, Bef[e][2], in); in = fmaf(bsA.w, Bef[e][3], in);
          in = fmaf(bsB.x, Bef[e][4], in); in = fmaf(bsB.y, Bef[e][5], in);
          in = fmaf(bsB.z, Bef[e][6], in); in = fmaf(bsB.w, Bef[e][7], in);
          const float gv = (e < 4) ? ((e == 0) ? g0.x : (e == 1) ? g0.y : (e == 2) ? g0.z : g0.w)
                                   : ((e == 4) ? g1.x : (e == 5) ? g1.y : (e == 6) ? g1.z : g1.w);
          acc = fmaf(gv, in, acc);
        }
        if (p3 == 0)      ((_Float16*)&xqrz[p][t][ln])[0] = (_Float16)acc;
        else if (p3 == 1) ((_Float16*)&xqrz[p][t][ln])[1] = (_Float16)acc;
        else              xqn[p][t][ln] = (_Float16)acc;
      }
    }

    // ---------- consumer: chunk ic-1 (R13 verbatim) ----------
    if (w == 0 && ic >= 1) {
      const int jc = ic - 1;
      const int p = jc & 1;
      const int tb = tstart + jc * CH_;
      const bool do_store = (jc >= wup);
      half2_t rz0 = u2h2(xqrz[p][0][ln]);
      float xr = (float)rz0.x, xz = (float)rz0.y;
      float xn = (float)xqn[p][0][ln];
      __builtin_amdgcn_s_setprio(1);
#pragma unroll 1
      for (int s = 0; s < CH_; ++s) {
        float ar0 = bhh3[0], ar1 = xr, ar2 = 0.f, ar3 = 0.f;
        float az0 = bhh3[1], az1 = xz, az2 = 0.f, az3 = 0.f;
        float an0 = bhh3[2], an1 = 0.f, an2 = 0.f, an3 = 0.f;
        DOTBLK(u0, 0) DOTBLK(u1, 4) DOTBLK(u2, 8) DOTBLK(u3, 12)
        DOTBLK(u4, 16) DOTBLK(u5, 20) DOTBLK(u6, 24) DOTBLK(u7, 28)
        const float hr = (ar0 + ar1) + (ar2 + ar3);
        const float hz = (az0 + az1) + (az2 + az3);
        const float hn = (an0 + an1) + (an2 + an3);
        const float r = frcp(1.0f + exp2_(hr));
        const float z = frcp(1.0f + exp2_(hz));
        const float tn = frcp(1.0f + exp2_(fmaf(r, hn, xn)));
        const float n = fmaf(2.0f, tn, -1.0f);
        h = n + z * (h - n);
        hbc[ln] = __builtin_bit_cast(unsigned short, (_Float16)h);
        asm volatile("" ::: "memory");
        const int sn = (s + 1) & (CH_ - 1);
        const unsigned rzn = xqrz[p][sn][ln];
        const _Float16 xnn = xqn[p][sn][ln];
        u0 = hq4[0]; u1 = hq4[1]; u2 = hq4[2]; u3 = hq4[3];
        u4 = hq4[4]; u5 = hq4[5]; u6 = hq4[6]; u7 = hq4[7];
        asm volatile("" ::: "memory");
        if (do_store) outrow[(size_t)(tb + s) * 96 + ln] = h;
        const half2_t rzh = u2h2(rzn);
        xr = (float)rzh.x; xz = (float)rzh.y; xn = (float)xnn;
      }
      __builtin_amdgcn_s_setprio(0);
    }
    __syncthreads();
  }

  // ======================= Conv tail: 8 tiles (R13 verbatim) =======================
  {
    auto fa  = (float (*)[136])smem_;
    auto cwl = (float (*)[161])(smem_ + 17408);
    auto swl = (float (*)[OUT_][KC_])(smem_ + 38016);
    auto bwl = (float (*)[OUT_])(smem_ + 46208);
    float* gwl = (float*)(smem_ + 47232);
    float* gbl = (float*)(smem_ + 47264);

    for (int i = tid; i < OUT_ * OUT_ * 5; i += 256) cwl[i / 160][i % 160] = cw[i];
    for (int i = tid; i < E_ * OUT_ * KC_; i += 256) ((float*)swl)[i] = swa[i];
    for (int i = tid; i < E_ * OUT_; i += 256) ((float*)bwl)[i] = bwa[i];
    if (tid < E_) { gwl[tid] = gwa[tid]; gbl[tid] = gba[tid]; }
    __syncthreads();

#pragma unroll 1
    for (int it = 0; it < 8; ++it) {
      const int t0 = (seg * 8 + it) * TILE_A;
      if (tid < TILE_A + 4) {
        const int i = tid;
        const int t = t0 + i - 2;
        const bool inr = (t >= 0) && (t < T_);
        const float x = inr ? a[db + t] : 0.0f;
        float gwr[E_], gbr[E_];
#pragma unroll
        for (int e = 0; e < E_; ++e) { gwr[e] = gwl[e]; gbr[e] = gbl[e]; }
        float silu, gate[E_], bs[KC_];
        kan_scalars(x, gwr, gbr, silu, gate, bs);
#pragma unroll 4
        for (int cc = 0; cc < OUT_; ++cc) {
          float accb = 0.f, accs = 0.f;
#pragma unroll
          for (int e = 0; e < E_; ++e) {
            accb = fmaf(gate[e], bwl[e][cc], accb);
            const float4 s0 = *(const float4*)&swl[e][cc][0];
            const float4 s1 = *(const float4*)&swl[e][cc][4];
            float dot = bs[0]*s0.x + bs[1]*s0.y + bs[2]*s0.z + bs[3]*s0.w
                      + bs[4]*s1.x + bs[5]*s1.y + bs[6]*s1.z + bs[7]*s1.w;
            accs = fmaf(gate[e], dot, accs);
          }
          fa[cc][i] = inr ? fmaf(silu, accb, accs) : 0.0f;
        }
      }
      __syncthreads();
      {
        const int o = tid & 31;
        const int grp = tid >> 5;
        const float bias = cb[o];
        float acc[16];
#pragma unroll
        for (int q = 0; q < 16; ++q) acc[q] = bias;
        for (int c = 0; c < OUT_; ++c) {
          float col[20];
#pragma unroll
          for (int q = 0; q < 5; ++q)
            *(float4*)&col[q * 4] = *(const float4*)&fa[c][grp * 16 + q * 4];
#pragma unroll
          for (int jj = 0; jj < 5; ++jj) {
            const float wv = cwl[o][c * 5 + jj];
#pragma unroll
            for (int q = 0; q < 16; ++q) acc[q] = fmaf(col[q + jj], wv, acc[q]);
          }
        }
#pragma unroll
        for (int q = 0; q < 16; ++q) {
          const int t = t0 + grp * 16 + q;
          out[(db + t) * 96 + o] = fmaxf(acc[q], 0.0f);
        }
      }
      __syncthreads();
    }
  }
}

extern "C" void kernel_launch(void* const* d_in, const int* in_sizes, int n_in,
                              void* d_out, int out_size, void* d_ws, size_t ws_size,
                              hipStream_t stream) {
  (void)in_sizes; (void)n_in; (void)out_size; (void)d_ws; (void)ws_size;
  const float* a        = (const float*)d_in[0];
  const float* d        = (const float*)d_in[1];
  const float* gate_w_a = (const float*)d_in[2];
  const float* gate_b_a = (const float*)d_in[3];
  const float* base_w_a = (const float*)d_in[4];
  const float* spln_w_a = (const float*)d_in[5];
  const float* gate_w_d = (const float*)d_in[6];
  const float* gate_b_d = (const float*)d_in[7];
  const float* base_w_d = (const float*)d_in[8];
  const float* spln_w_d = (const float*)d_in[9];
  const float* conv_w   = (const float*)d_in[10];
  const float* conv_b   = (const float*)d_in[11];
  const float* w_ih     = (const float*)d_in[12];
  const float* w_hh     = (const float*)d_in[13];
  const float* b_ih     = (const float*)d_in[14];
  const float* b_hh     = (const float*)d_in[15];
  float* out = (float*)d_out;

  fused10_kernel<<<NSEG * B_, 256, 0, stream>>>(
      a, d, gate_w_a, gate_b_a, base_w_a, spln_w_a,
      gate_w_d, gate_b_d, base_w_d, spln_w_d,
      conv_w, conv_b, w_ih, w_hh, b_ih, b_hh, out);
}